// Round 1
// baseline (1012.039 us; speedup 1.0000x reference)
//
#include <hip/hip_runtime.h>
#include <math.h>

#define NB  128
#define NI  512
#define NH  512
#define NO  512
#define N2  1024

// ---------------------------------------------------------------------------
// Fused pair-GEMM: C[b, n] for n in [0,1024):
//   n <  512: bias1[n] + A1[b,:]·Wa1[n,:] + A2[b,:]·Wb1[n,:]
//   n >= 512: bias2[m] + A1[b,:]·Wa2[m,:] + A2[b,:]·Wb2[m,:]   (m = n-512)
// One block per b-row (A staged in LDS, broadcast reads), thread per n.
// ---------------------------------------------------------------------------
__global__ __launch_bounds__(256) void gemm_pair(
    const float* __restrict__ A1, const float* __restrict__ A2,
    const float* __restrict__ Wa1, const float* __restrict__ Wb1, const float* __restrict__ bias1,
    const float* __restrict__ Wa2, const float* __restrict__ Wb2, const float* __restrict__ bias2,
    float* __restrict__ outp)
{
    __shared__ float a1s[NI];
    __shared__ float a2s[NH];
    const int b = blockIdx.y;
    for (int k = threadIdx.x; k < NI; k += 256) a1s[k] = A1[b * NI + k];
    for (int k = threadIdx.x; k < NH; k += 256) a2s[k] = A2[b * NH + k];
    __syncthreads();

    const int n = blockIdx.x * 256 + threadIdx.x;   // 0..1023, uniform half per block
    const float* wa;
    const float* wb;
    float acc;
    if (n < NH) { wa = Wa1 + n * NI;        wb = Wb1 + n * NH;        acc = bias1[n]; }
    else        { const int m = n - NH; wa = Wa2 + m * NI; wb = Wb2 + m * NH; acc = bias2[m]; }

#pragma unroll 4
    for (int k = 0; k < NI; k += 4) {
        const float4 w4 = *(const float4*)(wa + k);
        const float4 a4 = *(const float4*)(&a1s[k]);
        acc += w4.x * a4.x + w4.y * a4.y + w4.z * a4.z + w4.w * a4.w;
    }
#pragma unroll 4
    for (int k = 0; k < NH; k += 4) {
        const float4 w4 = *(const float4*)(wb + k);
        const float4 a4 = *(const float4*)(&a2s[k]);
        acc += w4.x * a4.x + w4.y * a4.y + w4.z * a4.z + w4.w * a4.w;
    }
    outp[b * N2 + n] = acc;
}

// ---------------------------------------------------------------------------
// Pointwise gate math on (B, NH): g, r, h, coefficients for the trace kernel,
// e_b updates, and the H_g count (openings numerator).
// ---------------------------------------------------------------------------
__global__ __launch_bounds__(256) void gates_kernel(
    const float* __restrict__ pre, const float* __restrict__ hlast,
    const float* __restrict__ e_bg, const float* __restrict__ e_br,
    float* __restrict__ c0, float* __restrict__ cgh, float* __restrict__ crh,
    float* __restrict__ o_h, float* __restrict__ o_ebg, float* __restrict__ o_ebr,
    float* __restrict__ acc)
{
    const int idx = blockIdx.x * 256 + threadIdx.x;   // 0..65535
    const int b = idx >> 9;
    const int j = idx & 511;

    const float ag = pre[b * N2 + j];
    const float ar = pre[b * N2 + NH + j];
    const float tg = tanhf(ag);
    const float g  = tg > 0.0f ? tg : 0.0f;           // relu(tanh)
    const float r  = tanhf(ar);
    const float hl = hlast[idx];
    const float one_m_g = 1.0f - g;
    const float Hg = g > 0.0f ? 1.0f : 0.0f;          // clip(ceil(g),0,1), g>=0
    const float dg = (1.0f - g * g) * Hg;
    const float dr = 1.0f - r * r;
    const float delta = r - hl;

    o_h[idx]   = g * r + one_m_g * hl;
    c0[idx]    = one_m_g;
    cgh[idx]   = dg * delta;
    crh[idx]   = dr * g;
    o_ebg[idx] = e_bg[idx] * one_m_g + dg * delta;
    o_ebr[idx] = e_br[idx] * one_m_g + dr * g;

    // block-reduce H_g, one atomic per block (counts are integers -> exact fp32)
    float v = Hg;
#pragma unroll
    for (int off = 32; off > 0; off >>= 1) v += __shfl_down(v, off, 64);
    __shared__ float red[4];
    const int lane = threadIdx.x & 63;
    const int w    = threadIdx.x >> 6;
    if (lane == 0) red[w] = v;
    __syncthreads();
    if (threadIdx.x == 0) atomicAdd(acc, red[0] + red[1] + red[2] + red[3]);
}

// ---------------------------------------------------------------------------
// out = sigmoid(a_o) * tanh(a_p)
// ---------------------------------------------------------------------------
__global__ __launch_bounds__(256) void out_kernel(
    const float* __restrict__ pre, float* __restrict__ o)
{
    const int idx = blockIdx.x * 256 + threadIdx.x;   // 0..65535
    const int b = idx >> 9;
    const int j = idx & 511;
    const float p  = tanhf(pre[b * N2 + j]);
    const float ao = pre[b * N2 + NO + j];
    const float oo = 1.0f / (1.0f + expf(-ao));
    o[idx] = oo * p;
}

// ---------------------------------------------------------------------------
// The big streaming kernel: 4 x (B,NH,NI) eligibility traces, float4 lanes.
//   e_gx_n = e_gx*(1-g) + (dg*delta)*x_i
//   e_gh_n = e_gh*(1-g) + (dg*delta)*h_i
//   e_rx_n = e_rx*(1-g) + (dr*g)*x_i
//   e_rh_n = e_rh*(1-g) + (dr*g)*h_i
// idx is in float4 units: i4 = idx&127 (i/4), bj = idx>>7, b = idx>>16.
// ---------------------------------------------------------------------------
__global__ __launch_bounds__(256) void traces_kernel(
    const float4* __restrict__ e_gx, const float4* __restrict__ e_gh,
    const float4* __restrict__ e_rx, const float4* __restrict__ e_rh,
    const float* __restrict__ x, const float* __restrict__ hlast,
    const float* __restrict__ c0, const float* __restrict__ cgh, const float* __restrict__ crh,
    float4* __restrict__ o_gx, float4* __restrict__ o_gh,
    float4* __restrict__ o_rx, float4* __restrict__ o_rh)
{
    const int idx = blockIdx.x * 256 + threadIdx.x;   // 0..8388607
    const int i4 = idx & 127;
    const int bj = idx >> 7;
    const int b  = idx >> 16;

    const float a0 = c0[bj];
    const float a1 = cgh[bj];
    const float a2 = crh[bj];
    const float4 x4 = ((const float4*)x)[b * 128 + i4];
    const float4 h4 = ((const float4*)hlast)[b * 128 + i4];

    float4 v;
    v = e_gx[idx];
    v.x = v.x * a0 + a1 * x4.x; v.y = v.y * a0 + a1 * x4.y;
    v.z = v.z * a0 + a1 * x4.z; v.w = v.w * a0 + a1 * x4.w;
    o_gx[idx] = v;

    v = e_gh[idx];
    v.x = v.x * a0 + a1 * h4.x; v.y = v.y * a0 + a1 * h4.y;
    v.z = v.z * a0 + a1 * h4.z; v.w = v.w * a0 + a1 * h4.w;
    o_gh[idx] = v;

    v = e_rx[idx];
    v.x = v.x * a0 + a2 * x4.x; v.y = v.y * a0 + a2 * x4.y;
    v.z = v.z * a0 + a2 * x4.z; v.w = v.w * a0 + a2 * x4.w;
    o_rx[idx] = v;

    v = e_rh[idx];
    v.x = v.x * a0 + a2 * h4.x; v.y = v.y * a0 + a2 * h4.y;
    v.z = v.z * a0 + a2 * h4.z; v.w = v.w * a0 + a2 * h4.w;
    o_rh[idx] = v;
}

__global__ void final_kernel(const float* __restrict__ acc, float* __restrict__ o)
{
    o[0] = acc[0] * (1.0f / 65536.0f);   // mean over B*NH
}

// ---------------------------------------------------------------------------
extern "C" void kernel_launch(void* const* d_in, const int* in_sizes, int n_in,
                              void* d_out, int out_size, void* d_ws, size_t ws_size,
                              hipStream_t stream)
{
    const float* x     = (const float*)d_in[0];
    const float* hlast = (const float*)d_in[1];
    const float* w_gx  = (const float*)d_in[2];
    const float* w_gh  = (const float*)d_in[3];
    const float* b_g   = (const float*)d_in[4];
    const float* w_rx  = (const float*)d_in[5];
    const float* w_rh  = (const float*)d_in[6];
    const float* b_r   = (const float*)d_in[7];
    const float* w_px  = (const float*)d_in[8];
    const float* w_ph  = (const float*)d_in[9];
    const float* b_p   = (const float*)d_in[10];
    const float* w_ox  = (const float*)d_in[11];
    const float* w_oh  = (const float*)d_in[12];
    const float* b_o   = (const float*)d_in[13];
    const float* e_gx  = (const float*)d_in[14];
    const float* e_gh  = (const float*)d_in[15];
    const float* e_bg  = (const float*)d_in[16];
    const float* e_rx  = (const float*)d_in[17];
    const float* e_rh  = (const float*)d_in[18];
    const float* e_br  = (const float*)d_in[19];

    float* out    = (float*)d_out;
    float* o_out  = out;                // (128,512)      65536
    float* o_h    = out + 65536;        // (128,512)      65536
    float* o_egx  = out + 131072;       // (128,512,512)  33554432
    float* o_egh  = out + 33685504;     // (128,512,512)
    float* o_ebg  = out + 67239936;     // (128,512)
    float* o_erx  = out + 67305472;     // (128,512,512)
    float* o_erh  = out + 100859904;    // (128,512,512)
    float* o_ebr  = out + 134414336;    // (128,512)
    float* o_open = out + 134479872;    // scalar

    float* ws  = (float*)d_ws;
    float* pre = ws;                    // 131072 floats, reused by both GEMMs
    float* c0  = ws + 131072;           // 65536
    float* cgh = ws + 196608;           // 65536
    float* crh = ws + 262144;           // 65536
    float* acc = ws + 327680;           // 1

    hipMemsetAsync(acc, 0, sizeof(float), stream);

    const dim3 gg(4, NB);
    gemm_pair<<<gg, 256, 0, stream>>>(x, hlast, w_gx, w_gh, b_g, w_rx, w_rh, b_r, pre);
    gates_kernel<<<256, 256, 0, stream>>>(pre, hlast, e_bg, e_br,
                                          c0, cgh, crh, o_h, o_ebg, o_ebr, acc);
    gemm_pair<<<gg, 256, 0, stream>>>(x, o_h, w_px, w_ph, b_p, w_ox, w_oh, b_o, pre);
    out_kernel<<<256, 256, 0, stream>>>(pre, o_out);
    traces_kernel<<<32768, 256, 0, stream>>>(
        (const float4*)e_gx, (const float4*)e_gh, (const float4*)e_rx, (const float4*)e_rh,
        x, hlast, c0, cgh, crh,
        (float4*)o_egx, (float4*)o_egh, (float4*)o_erx, (float4*)o_erh);
    final_kernel<<<1, 1, 0, stream>>>(acc, o_open);
}